// Round 2
// baseline (355.628 us; speedup 1.0000x reference)
//
#include <hip/hip_runtime.h>

// Problem constants (B, F, V, D) = (16384, 16, 300000, 10)
#define Bsz   16384
#define Fn    16
#define Vn    300000
#define Dn    10
#define NPAIR 120           // F*(F-1)/2
#define OUT_ROW 1376        // 120*10 + 16*10 + 16
#define ROWS_PER_BLOCK 4    // one wave (64 lanes) per row

// triu(k=1) pair table, row-major order, packed i*16+j
__device__ const unsigned char PAIR_IJ[NPAIR] = {
    1,2,3,4,5,6,7,8,9,10,11,12,13,14,15,
    18,19,20,21,22,23,24,25,26,27,28,29,30,31,
    35,36,37,38,39,40,41,42,43,44,45,46,47,
    52,53,54,55,56,57,58,59,60,61,62,63,
    69,70,71,72,73,74,75,76,77,78,79,
    86,87,88,89,90,91,92,93,94,95,
    103,104,105,106,107,108,109,110,111,
    120,121,122,123,124,125,126,127,
    137,138,139,140,141,142,143,
    154,155,156,157,158,159,
    171,172,173,174,175,
    188,189,190,191,
    205,206,207,
    222,223,
    239
};

__global__ __launch_bounds__(256) void ffm_kernel(
    const int*   __restrict__ x,     // (B, F)
    const float* __restrict__ emb,   // (F, V, D)
    const float* __restrict__ lin,   // (V, 1)
    float*       __restrict__ out)   // (B, OUT_ROW)
{
    // tile[w][f][g][d] = emb[g, x[row_w, f], d]
    __shared__ float tile[ROWS_PER_BLOCK][Fn][Fn][Dn];   // 40 KB

    const int w    = threadIdx.x >> 6;
    const int lane = threadIdx.x & 63;
    const int row  = blockIdx.x * ROWS_PER_BLOCK + w;

    // each lane holds x[row, lane&15]; broadcast via __shfl while CONVERGED
    const int xv = x[row * Fn + (lane & 15)];

    // lin gather while fully converged (redundant 4x across the wave, cheap;
    // MUST NOT be done under divergence: shuffle-from-inactive-lane is UB)
    const float lv = lin[xv];

    // ---- gather phase: 256 vectors of 10 floats, 4 per lane ----
    // issue all 20 float2 loads before any LDS write (MLP)
    float2 buf[4][5];
    #pragma unroll
    for (int t = 0; t < 4; ++t) {
        const int q = lane + 64 * t;      // 0..255
        const int f = q >> 4;
        const int g = q & 15;
        const int idx = __shfl(xv, f);
        const float2* src = (const float2*)(emb + ((size_t)g * Vn + (size_t)idx) * Dn);
        #pragma unroll
        for (int c = 0; c < 5; ++c) buf[t][c] = src[c];
    }
    #pragma unroll
    for (int t = 0; t < 4; ++t) {
        const int q = lane + 64 * t;
        const int f = q >> 4;
        const int g = q & 15;
        float2* dst = (float2*)&tile[w][f][g][0];
        #pragma unroll
        for (int c = 0; c < 5; ++c) dst[c] = buf[t][c];
    }
    __syncthreads();

    // ---- compute + store phase: coalesced stride-64 over cols 0..1359 ----
    float* orow = out + (size_t)row * OUT_ROW;
    for (int k = lane; k < 1360; k += 64) {
        float val;
        if (k < 1200) {
            const int p = k / 10;
            const int d = k - p * 10;
            const int ij = PAIR_IJ[p];
            const int i = ij >> 4, j = ij & 15;
            val = tile[w][i][j][d] * tile[w][j][i][d];
        } else {
            const int t2 = k - 1200;
            const int f = t2 / 10;
            const int d = t2 - f * 10;
            val = tile[w][f][f][d];
        }
        orow[k] = val;
    }

    // ---- lin columns 1360..1375: lane f stores lin[x[row, f]] ----
    if (lane < Fn) {
        orow[1360 + lane] = lv;
    }
}

extern "C" void kernel_launch(void* const* d_in, const int* in_sizes, int n_in,
                              void* d_out, int out_size, void* d_ws, size_t ws_size,
                              hipStream_t stream) {
    const int*   x   = (const int*)d_in[0];
    const float* emb = (const float*)d_in[1];
    const float* lin = (const float*)d_in[2];
    float*       out = (float*)d_out;

    const int blocks = Bsz / ROWS_PER_BLOCK;   // 4096
    ffm_kernel<<<blocks, 256, 0, stream>>>(x, emb, lin, out);
}

// Round 4
// 342.975 us; speedup vs baseline: 1.0369x; 1.0369x over previous
//
#include <hip/hip_runtime.h>

// Problem constants (B, F, V, D) = (16384, 16, 300000, 10)
#define Bsz   16384
#define Fn    16
#define Vn    300000
#define Dn    10
#define OUT_ROW 1376        // 120*10 + 16*10 + 16
#define ROWS_PER_BLOCK 4    // one wave (64 lanes) per row, zero LDS

// triu(k=1) pair table, row-major order, packed i*16+j
__device__ const unsigned char PAIR_IJ[120] = {
    1,2,3,4,5,6,7,8,9,10,11,12,13,14,15,
    18,19,20,21,22,23,24,25,26,27,28,29,30,31,
    35,36,37,38,39,40,41,42,43,44,45,46,47,
    52,53,54,55,56,57,58,59,60,61,62,63,
    69,70,71,72,73,74,75,76,77,78,79,
    86,87,88,89,90,91,92,93,94,95,
    103,104,105,106,107,108,109,110,111,
    120,121,122,123,124,125,126,127,
    137,138,139,140,141,142,143,
    154,155,156,157,158,159,
    171,172,173,174,175,
    188,189,190,191,
    205,206,207,
    222,223,
    239
};

// RULE (learned R1+R3): every __shfl must execute with all 64 lanes converged.
__global__ __launch_bounds__(256, 8) void ffm_kernel(
    const int*   __restrict__ x,     // (B, F)
    const float* __restrict__ emb,   // (F, V, D)
    const float* __restrict__ lin,   // (V, 1)
    float*       __restrict__ out)   // (B, OUT_ROW)
{
    const int wave = threadIdx.x >> 6;
    const int lane = threadIdx.x & 63;
    const int row  = blockIdx.x * ROWS_PER_BLOCK + wave;

    // lane holds x[row, lane&15]
    const int xv = x[row * Fn + (lane & 15)];
    float* orow = out + (size_t)row * OUT_ROW;

    // ---- epilogue operands, computed CONVERGED ----
    // lin: lane 16+f naturally holds lin[x[row,f]] since lane&15==f
    const float lv = lin[xv];
    // self terms for cols 1344..1359 (handled by lanes 0..15):
    // t2 = 144 + (lane&15) in 144..159, f = t2/10 in {14,15}, d = t2%10
    const int t2   = 144 + (lane & 15);
    const int f_ep = t2 / 10;
    const int d_ep = t2 - f_ep * 10;
    const int xf_ep = __shfl(xv, f_ep);               // converged
    const float self_ep = emb[(unsigned)(f_ep * Vn + xf_ep) * 10u + d_ep];

    // ---- main loop: k = lane + 64*it, it = 0..20 (k <= 1343, converged) ----
    #pragma unroll 3
    for (int it = 0; it < 21; ++it) {
        const int k = lane + (it << 6);
        const int p = k / 10;                 // magic-mul
        const int d = k - p * 10;
        const bool isPair = k < 1200;
        const int pc = isPair ? p : 0;
        const int ij = PAIR_IJ[pc];
        const int f  = p - 120;               // valid when !isPair
        const int i  = isPair ? (ij >> 4) : f;
        const int j  = isPair ? (ij & 15) : f;
        const int xi = __shfl(xv, i);         // converged
        const int xj = __shfl(xv, j);         // converged
        // offsets fit 32-bit: (15*300000+299999)*10+9 < 2^26
        const float A = emb[(unsigned)(j * Vn + xi) * 10u + d];
        const float B = emb[(unsigned)(i * Vn + xj) * 10u + d];
        orow[k] = isPair ? A * B : A;
    }

    // ---- epilogue stores: cols 1344..1375, lanes 0..31 (no shuffles here) ----
    if (lane < 32) {
        orow[1344 + lane] = (lane < 16) ? self_ep : lv;
    }
}

extern "C" void kernel_launch(void* const* d_in, const int* in_sizes, int n_in,
                              void* d_out, int out_size, void* d_ws, size_t ws_size,
                              hipStream_t stream) {
    const int*   x   = (const int*)d_in[0];
    const float* emb = (const float*)d_in[1];
    const float* lin = (const float*)d_in[2];
    float*       out = (float*)d_out;

    const int blocks = Bsz / ROWS_PER_BLOCK;   // 4096
    ffm_kernel<<<blocks, 256, 0, stream>>>(x, emb, lin, out);
}

// Round 5
// 341.813 us; speedup vs baseline: 1.0404x; 1.0034x over previous
//
#include <hip/hip_runtime.h>

// Problem constants (B, F, V, D) = (16384, 16, 300000, 10)
#define Bsz   16384
#define Fn    16
#define Vn    300000
#define Dn    10
#define OUT_ROW 1376        // 120*10 + 16*10 + 16
#define ROWS_PER_BLOCK 4    // one wave per row, zero LDS

// triu(k=1) pair table, row-major order, packed i*16+j
__device__ const unsigned char PAIR_IJ[120] = {
    1,2,3,4,5,6,7,8,9,10,11,12,13,14,15,
    18,19,20,21,22,23,24,25,26,27,28,29,30,31,
    35,36,37,38,39,40,41,42,43,44,45,46,47,
    52,53,54,55,56,57,58,59,60,61,62,63,
    69,70,71,72,73,74,75,76,77,78,79,
    86,87,88,89,90,91,92,93,94,95,
    103,104,105,106,107,108,109,110,111,
    120,121,122,123,124,125,126,127,
    137,138,139,140,141,142,143,
    154,155,156,157,158,159,
    171,172,173,174,175,
    188,189,190,191,
    205,206,207,
    222,223,
    239
};

// RULE (R1+R3): every __shfl executes with all 64 lanes converged.
// launch_bounds(256,6): cap ~84 VGPR -> 24 waves/CU; full-unroll MLP is the lever.
__global__ __launch_bounds__(256, 6) void ffm_kernel(
    const int*   __restrict__ x,     // (B, F)
    const float* __restrict__ emb,   // (F, V, D)
    const float* __restrict__ lin,   // (V, 1)
    float*       __restrict__ out)   // (B, OUT_ROW)
{
    const int wave = threadIdx.x >> 6;
    const int lane = threadIdx.x & 63;
    const int row  = blockIdx.x * ROWS_PER_BLOCK + wave;

    const int xv = x[row * Fn + (lane & 15)];   // lane 16a+f holds x[row,f]
    float* orow = out + (size_t)row * OUT_ROW;
    const float lv = lin[xv];                   // converged; lanes 16..31 store it

    // ---- tail operands (cols 1280..1359, self region), computed CONVERGED ----
    // k0t = 1280 + 2*lane; lanes 0..39 cover the 80 floats
    const int k0t = 1280 + 2 * lane;
    const int pt  = k0t / 10;                   // 128..140 across lanes
    const int d0t = k0t - pt * 10;              // even
    const int ft  = pt - 120;                   // 8..20; only <16 is real
    const int fts = (ft < 16) ? ft : 0;         // clamp shuffle src (lanes 40+ unused)
    const int xft = __shfl(xv, fts);            // CONVERGED
    float2 tailv = make_float2(0.f, 0.f);
    if (lane < 40) {                            // load under divergence is fine
        tailv = *(const float2*)(emb + (unsigned)(fts * Vn + xft) * 10u + d0t);
    }

    // ---- main: k0 = 2*lane + 128*it, it=0..9 covers cols 0..1279 ----
    // it<=8 pure pair region; it=9 mixes pair (p<120) and self (p>=120).
    // Issue ALL 20 dwordx2 loads before any store (MLP).
    float2 A[10], Bv[10];
    bool   pr[10];
    #pragma unroll
    for (int it = 0; it < 10; ++it) {
        const int k0 = 2 * lane + (it << 7);
        const int p  = k0 / 10;                 // magic-mul
        const int d0 = k0 - p * 10;             // even
        const bool isPair = p < 120;
        pr[it] = isPair;
        const int ij = PAIR_IJ[isPair ? p : 0];
        const int f  = p - 120;                 // 0..7 when self (it=9 only)
        const int i  = isPair ? (ij >> 4) : f;
        const int j  = isPair ? (ij & 15) : f;
        const int xi = __shfl(xv, i);           // CONVERGED
        const int xj = __shfl(xv, j);           // CONVERGED
        A[it]  = *(const float2*)(emb + (unsigned)(j * Vn + xi) * 10u + d0);
        Bv[it] = *(const float2*)(emb + (unsigned)(i * Vn + xj) * 10u + d0);
    }
    #pragma unroll
    for (int it = 0; it < 10; ++it) {
        const int k0 = 2 * lane + (it << 7);
        float2 r;
        r.x = pr[it] ? A[it].x * Bv[it].x : A[it].x;
        r.y = pr[it] ? A[it].y * Bv[it].y : A[it].y;
        *(float2*)(orow + k0) = r;
    }

    // ---- tail stores ----
    if (lane < 40) {
        *(float2*)(orow + k0t) = tailv;         // cols 1280..1359
    }
    if (lane >= 16 && lane < 32) {
        orow[1344 + lane] = lv;                 // cols 1360..1375 (lane&15 == f)
    }
}

extern "C" void kernel_launch(void* const* d_in, const int* in_sizes, int n_in,
                              void* d_out, int out_size, void* d_ws, size_t ws_size,
                              hipStream_t stream) {
    const int*   x   = (const int*)d_in[0];
    const float* emb = (const float*)d_in[1];
    const float* lin = (const float*)d_in[2];
    float*       out = (float*)d_out;

    const int blocks = Bsz / ROWS_PER_BLOCK;   // 4096
    ffm_kernel<<<blocks, 256, 0, stream>>>(x, emb, lin, out);
}